// Round 9
// baseline (239.022 us; speedup 1.0000x reference)
//
#include <hip/hip_runtime.h>
#include <hip/hip_fp16.h>

#define Hh 1024
#define Ww 1024
#define PO 12        // halo offset (>= T+2)
#define PS 1048      // padded row stride = 1024 + 2*PO
#define PH 524       // padded half-row (deinterleaved even/odd planes)
#define T 10         // fused iterations per launch (100 = 10 launches x 10)
#define TILE 64      // output tile per block
#define RG 84        // region = TILE + 2T
#define HS 43        // LDS half-row stride in u32 (ODD -> all 32 banks)
#define PL (RG * HS) // 3612 u32 per plane per buffer

typedef unsigned int u32;

// packed per-pixel weights: 8 x fp16 in one 16B struct (w0..w7)
struct alignas(16) W8 { __half2 a, b, c, d; };

__device__ inline __half2 h2(u32 v) { return *(__half2*)&v; }
__device__ inline u32 u2(__half2 v) { return *(u32*)&v; }

// packed-weight FMA: w holds TWO weights (lo,hi); op_sel broadcasts the
// selected half across both lanes of the packed fma. Register-only VALU asm.
__device__ inline void fma_lo(u32& acc, u32 w, u32 x) {
    asm("v_pk_fma_f16 %0, %1, %2, %0 op_sel_hi:[0,1,1]"
        : "+v"(acc) : "v"(w), "v"(x));
}
__device__ inline void fma_hi(u32& acc, u32 w, u32 x) {
    asm("v_pk_fma_f16 %0, %1, %2, %0 op_sel:[1,0,0] op_sel_hi:[1,1,1]"
        : "+v"(acc) : "v"(w), "v"(x));
}

// address-space typedefs for global_load_lds (async global->LDS DMA)
typedef __attribute__((address_space(3))) u32 lds_u32_t;
typedef __attribute__((address_space(1))) const u32 glb_u32_t;

// ---------------------------------------------------------------------------
// prep: Ypad (luma), x state as DEINTERLEAVED half2 planes (even cols -> E,
// odd cols -> O; plane idx = padded_col>>1). buf0 = b (IQ if colored else 0,
// zero halo), buf1 = 0. mask = isColored.
// ---------------------------------------------------------------------------
__global__ __launch_bounds__(256)
void prep_kernel(const float* __restrict__ gray, const float* __restrict__ app,
                 float* __restrict__ Ypad,
                 u32* __restrict__ xE0, u32* __restrict__ xO0,
                 u32* __restrict__ xE1, u32* __restrict__ xO1,
                 unsigned char* __restrict__ mask) {
    int px = blockIdx.x * 64 + threadIdx.x;
    int py = blockIdx.y * 4 + threadIdx.y;
    if (px >= PS || py >= PS) return;
    int i = py - PO, j = px - PO;
    float yv = 0.f;
    float2 bv = make_float2(0.f, 0.f);
    if (i >= 0 && i < Hh && j >= 0 && j < Ww) {
        int idx = i * Ww + j;
        const float s = 1.f / 255.f;
        float gr = gray[idx * 3 + 0] * s;
        float gg = gray[idx * 3 + 1] * s;
        float gb = gray[idx * 3 + 2] * s;
        float ar = app[idx * 3 + 0] * s;
        float ag = app[idx * 3 + 1] * s;
        float ab = app[idx * 3 + 2] * s;
        float diff = fabsf(gr - ar) + fabsf(gg - ag) + fabsf(gb - ab);
        bool colored = diff > 0.01f;
        yv = 0.3f * gr + 0.59f * gg + 0.11f * gb;
        float ay = 0.3f * ar + 0.59f * ag + 0.11f * ab;
        float ai = 0.74f * (ar - ay) - 0.27f * (ab - ay);
        float aq = 0.48f * (ar - ay) + 0.41f * (ab - ay);
        if (colored) bv = make_float2(ai, aq);
        mask[idx] = colored ? 1 : 0;
    }
    Ypad[py * PS + px] = yv;
    u32 hval = u2(__floats2half2_rn(bv.x, bv.y));
    int p = py * PH + (px >> 1);
    if (px & 1) { xO0[p] = hval; xO1[p] = 0u; }
    else        { xE0[p] = hval; xE1[p] = 0u; }
}

// ---------------------------------------------------------------------------
// weights: per padded pixel, 8 normalized neighbor weights packed fp16 (16B).
// ---------------------------------------------------------------------------
__global__ __launch_bounds__(256)
void weights_kernel(const float* __restrict__ Ypad,
                    const unsigned char* __restrict__ mask,
                    W8* __restrict__ w) {
    int px = blockIdx.x * 64 + threadIdx.x;
    int py = blockIdx.y * 4 + threadIdx.y;
    if (px >= PS || py >= PS) return;
    int p = py * PS + px;
    int i = py - PO, j = px - PO;
    W8 out;
    out.a = __floats2half2_rn(0.f, 0.f);
    out.b = out.a; out.c = out.a; out.d = out.a;
    if (i >= 0 && i < Hh && j >= 0 && j < Ww) {
        float yc = Ypad[p];
        float yn[8];
        yn[0] = Ypad[p - PS - 1]; yn[1] = Ypad[p - PS]; yn[2] = Ypad[p - PS + 1];
        yn[3] = Ypad[p - 1];                            yn[4] = Ypad[p + 1];
        yn[5] = Ypad[p + PS - 1]; yn[6] = Ypad[p + PS]; yn[7] = Ypad[p + PS + 1];
        float vt = (i > 0) ? 1.f : 0.f;
        float vb = (i < Hh - 1) ? 1.f : 0.f;
        float vl = (j > 0) ? 1.f : 0.f;
        float vr = (j < Ww - 1) ? 1.f : 0.f;
        float v[8] = { vt * vl, vt, vt * vr, vl, vr, vb * vl, vb, vb * vr };

        float count = 1.f, s1 = yc;
#pragma unroll
        for (int k = 0; k < 8; ++k) { count += v[k]; s1 += v[k] * yn[k]; }
        float mean = s1 / count;
        float var = (yc - mean) * (yc - mean);
#pragma unroll
        for (int k = 0; k < 8; ++k) { float d = yn[k] - mean; var += v[k] * d * d; }
        var /= count;
        float vs = fmaxf(0.6f * var, 2e-6f);
        float inv_vs = 1.f / vs;

        float wk[8], ws = 0.f;
#pragma unroll
        for (int k = 0; k < 8; ++k) {
            float d = yn[k] - yc;
            wk[k] = v[k] * expf(-d * d * inv_vs);
            ws += wk[k];
        }
        if (mask[i * Ww + j]) {
            out.a = __floats2half2_rn(-0.0f, 0.f);  // sign bit => keep center
        } else {
            float scale = 1.f / ws;
            out.a = __floats2half2_rn(wk[0] * scale, wk[1] * scale);
            out.b = __floats2half2_rn(wk[2] * scale, wk[3] * scale);
            out.c = __floats2half2_rn(wk[4] * scale, wk[5] * scale);
            out.d = __floats2half2_rn(wk[6] * scale, wk[7] * scale);
        }
    }
    w[p] = out;
}

// ---------------------------------------------------------------------------
// iter10p R20: R19 + TRAPEZOIDAL SHRINK. At iter t only region rows/cols
// [t+1, 82-t] can influence the final 64^2 tile (write range at t == read
// range at t+1, by induction; writes outside are never read -> guards are
// pure optimization, zero correctness risk). Skipping the dead border saves
// ~11% of row-iters (wave-level skip) and ~10% of lanes (col mask) -> about
// 15-20% of t-loop LDS bandwidth + FMA. Sliding window kept consistent via
// lazy winit (first in-range row loads u/m fresh); wq[i] indices stay
// compile-time (no runtime-indexed register arrays).
// ---------------------------------------------------------------------------
__global__ __launch_bounds__(1024, 4)
void iter10p_kernel(const u32* __restrict__ xE_in, const u32* __restrict__ xO_in,
                    u32* __restrict__ xE_out, u32* __restrict__ xO_out,
                    const W8* __restrict__ w, const float* __restrict__ Ypad,
                    float* __restrict__ out, int writeRGB) {
    __shared__ __align__(16) u32 xs[2][2][PL];   // [buf][plane][row*HS+col/2]
    int tid = threadIdx.x;

    // XCD swizzle (256 % 8 == 0 -> bijective); 16x16 tile grid
    int bid  = (int)blockIdx.y * 16 + (int)blockIdx.x;
    int nbid = (bid & 7) * 32 + (bid >> 3);
    int gi0 = (nbid >> 4) * TILE - T;
    int gj0 = (nbid & 15) * TILE - T;

    // async stage: waves 0..13 stage 6 region rows each (rows 6w..6w+5), both
    // planes; lanes 0..41 carry one u32 per plane-row (42 u32/plane-row).
    {
        int wv = tid >> 6;
        int ln = tid & 63;
        if (wv < 14 && ln < 42) {
            int ch = (gj0 + PO) >> 1;
            const u32* gE = xE_in + (size_t)(gi0 + wv * 6 + PO) * PH + ch + ln;
            const u32* gO = xO_in + (size_t)(gi0 + wv * 6 + PO) * PH + ch + ln;
#pragma unroll 1
            for (int k = 0; k < 6; ++k) {
                __builtin_amdgcn_global_load_lds((glb_u32_t*)(gE + (size_t)k * PH),
                                                 (lds_u32_t*)&xs[0][0][(wv * 6 + k) * HS],
                                                 4, 0, 0);
                __builtin_amdgcn_global_load_lds((glb_u32_t*)(gO + (size_t)k * PH),
                                                 (lds_u32_t*)&xs[0][1][(wv * 6 + k) * HS],
                                                 4, 0, 0);
            }
        }
    }

    // 861 active threads: strip = tid/41 (21 strips of 4 rows), cp = tid%41.
    // rows r0=1+4*strip .. r0+3; cols c0=1+2cp (odd), c0+1 (even).
    bool active = tid < 861;
    int strip = tid / 41;
    int cp = tid - strip * 41;
    int r0 = 1 + 4 * strip;
    int c0 = 1 + 2 * cp;

    // weights: up to 4 px-pairs/thread, PACKED (4 u32 per px) + keep-masks.
    u32 wq[4][8];
    u32 kL[4], kR[4];
    if (active) {
#pragma unroll
        for (int i = 0; i < 4; ++i) {
            kL[i] = 0u; kR[i] = 0u;
            if (r0 + i <= 82) {
                int gp = (gi0 + r0 + i + PO) * PS + (gj0 + c0 + PO);
                const uint4* wp = (const uint4*)(w + gp);
                uint4 wa = wp[0];
                uint4 wb = wp[1];
                wq[i][0] = wa.x; wq[i][1] = wa.y; wq[i][2] = wa.z; wq[i][3] = wa.w;
                wq[i][4] = wb.x; wq[i][5] = wb.y; wq[i][6] = wb.z; wq[i][7] = wb.w;
                kL[i] = (wa.x & 0x8000u) ? 0xFFFFFFFFu : 0u;
                kR[i] = (wb.x & 0x8000u) ? 0xFFFFFFFFu : 0u;
            }
        }
    }
    __syncthreads();   // drains the DMA + makes staged region visible

    int cur = 0;
#pragma unroll 1
    for (int t = 0; t < T; ++t) {        // rolled: no t-dependence inside
        int nxt = cur ^ 1;
        int lo = t + 1, hi = 82 - t;     // live trapezoid at this iteration
        if (active && c0 <= hi && c0 + 1 >= lo) {
            const u32* xe = xs[cur][0];
            const u32* xo = xs[cur][1];
            u32* xen = xs[nxt][0];
            u32* xon = xs[nxt][1];
            u32 u0x = 0, u0y = 0, u1x = 0, u1y = 0;
            u32 m0x = 0, m0y = 0, m1x = 0, m1y = 0;
            bool winit = false;
#pragma unroll
            for (int i = 0; i < 4; ++i) {
                int r = r0 + i;
                if (r >= lo && r <= hi) {
                    if (!winit) {
                        int rb = (r - 1) * HS + cp;
                        u0x = xe[rb]; u0y = xo[rb]; u1x = xe[rb + 1]; u1y = xo[rb + 1];
                        rb += HS;
                        m0x = xe[rb]; m0y = xo[rb]; m1x = xe[rb + 1]; m1y = xo[rb + 1];
                        winit = true;
                    }
                    int rd = (r + 1) * HS + cp;
                    u32 d0x = xe[rd], d0y = xo[rd], d1x = xe[rd + 1], d1y = xo[rd + 1];

                    u32 accL = kL[i] & m0y;            // center = col c0 (odd)
                    fma_lo(accL, wq[i][0], u0x);
                    fma_hi(accL, wq[i][0], u0y);
                    fma_lo(accL, wq[i][1], u1x);
                    fma_hi(accL, wq[i][1], m0x);
                    fma_lo(accL, wq[i][2], m1x);
                    fma_hi(accL, wq[i][2], d0x);
                    fma_lo(accL, wq[i][3], d0y);
                    fma_hi(accL, wq[i][3], d1x);

                    u32 accR = kR[i] & m1x;            // center = col c0+1 (even)
                    fma_lo(accR, wq[i][4], u0y);
                    fma_hi(accR, wq[i][4], u1x);
                    fma_lo(accR, wq[i][5], u1y);
                    fma_hi(accR, wq[i][5], m0y);
                    fma_lo(accR, wq[i][6], m1y);
                    fma_hi(accR, wq[i][6], d0y);
                    fma_lo(accR, wq[i][7], d1x);
                    fma_hi(accR, wq[i][7], d1y);

                    int wb = r * HS + cp;
                    xon[wb]     = accL;                // col c0   (odd plane)
                    xen[wb + 1] = accR;                // col c0+1 (even plane)

                    u0x = m0x; u0y = m0y; u1x = m1x; u1y = m1y;
                    m0x = d0x; m0y = d0y; m1x = d1x; m1y = d1y;
                }
            }
        }
        __syncthreads();
        cur = nxt;
    }

    if (!writeRGB) {
        // write central 64x64 tile (region rows/cols 10..73) to planes
#pragma unroll
        for (int k = 0; k < 4; ++k) {
            int pidx = tid + k * 1024;
            int r = T + (pidx >> 6), c = T + (pidx & 63);
            u32 val = xs[cur][c & 1][r * HS + (c >> 1)];
            u32* pl = (c & 1) ? xO_out : xE_out;
            pl[(size_t)(gi0 + r + PO) * PH + ((gj0 + PO + c) >> 1)] = val;
        }
    } else {
        // fused final: yiq -> rgb, clip, *255 straight from LDS
#pragma unroll
        for (int k = 0; k < 4; ++k) {
            int pidx = tid + k * 1024;
            int r = T + (pidx >> 6), c = T + (pidx & 63);
            int gi = gi0 + r, gj = gj0 + c;
            float y = Ypad[(gi + PO) * PS + (gj + PO)];
            u32 pxv = xs[cur][c & 1][r * HS + (c >> 1)];
            float2 iq = __half22float2(h2(pxv));
            float R_ = y + 0.9468822170900693f * iq.x + 0.6235565819861433f * iq.y;
            float G_ = y - 0.27478764629897834f * iq.x - 0.6356910791873801f * iq.y;
            float B_ = y - 1.1085450346420322f * iq.x + 1.7090069284064666f * iq.y;
            int idx = gi * Ww + gj;
            out[idx * 3 + 0] = fminf(fmaxf(R_, 0.f), 1.f) * 255.f;
            out[idx * 3 + 1] = fminf(fmaxf(G_, 0.f), 1.f) * 255.f;
            out[idx * 3 + 2] = fminf(fmaxf(B_, 0.f), 1.f) * 255.f;
        }
    }
}

extern "C" void kernel_launch(void* const* d_in, const int* in_sizes, int n_in,
                              void* d_out, int out_size, void* d_ws, size_t ws_size,
                              hipStream_t stream) {
    const float* gray = (const float*)d_in[0];
    const float* app  = (const float*)d_in[1];
    float* out = (float*)d_out;

    char* ws = (char*)d_ws;
    size_t off = 0;
    auto alloc = [&](size_t bytes) -> void* {
        void* r = ws + off;
        off = (off + bytes + 255) & ~(size_t)255;
        return r;
    };
    float* Ypad = (float*)alloc((size_t)PS * PS * sizeof(float));
    W8*    w    = (W8*)   alloc((size_t)PS * PS * sizeof(W8));
    unsigned char* mask = (unsigned char*)alloc((size_t)Hh * Ww);
    u32*   xE0  = (u32*)  alloc((size_t)PS * PH * sizeof(u32));
    u32*   xO0  = (u32*)  alloc((size_t)PS * PH * sizeof(u32));
    u32*   xE1  = (u32*)  alloc((size_t)PS * PH * sizeof(u32));
    u32*   xO1  = (u32*)  alloc((size_t)PS * PH * sizeof(u32));

    dim3 blk(64, 4);
    dim3 gridPad((PS + 63) / 64, (PS + 3) / 4);
    prep_kernel<<<gridPad, blk, 0, stream>>>(gray, app, Ypad, xE0, xO0, xE1, xO1, mask);
    weights_kernel<<<gridPad, blk, 0, stream>>>(Ypad, mask, w);

    dim3 gridIter(Ww / TILE, Hh / TILE);  // 16 x 16 = 256 blocks (1 per CU)
    u32 *iE = xE0, *iO = xO0, *oE = xE1, *oO = xO1;
    for (int l = 0; l < 10; ++l) {        // 10 x 10 = 100 iterations
        int last = (l == 9) ? 1 : 0;
        iter10p_kernel<<<gridIter, 1024, 0, stream>>>(iE, iO, oE, oO, w, Ypad, out, last);
        u32* t0 = iE; iE = oE; oE = t0;
        u32* t1 = iO; iO = oO; oO = t1;
    }
}

// Round 10
// 218.831 us; speedup vs baseline: 1.0923x; 1.0923x over previous
//
#include <hip/hip_runtime.h>
#include <hip/hip_fp16.h>

#define Hh 1024
#define Ww 1024
#define PO 12        // halo offset (>= T+2)
#define PS 1048      // padded row stride = 1024 + 2*PO
#define PH 524       // padded half-row (deinterleaved even/odd planes)
#define T 10         // fused iterations per launch (100 = 10 launches x 10)
#define TILE 64      // output tile per block
#define RG 84        // region = TILE + 2T
#define HS 43        // LDS half-row stride in u32 (ODD -> all 32 banks)
#define PL (RG * HS) // 3612 u32 per plane per buffer

typedef unsigned int u32;

// packed per-pixel weights: 8 x fp16 in one 16B struct (w0..w7)
struct alignas(16) W8 { __half2 a, b, c, d; };

__device__ inline __half2 h2(u32 v) { return *(__half2*)&v; }
__device__ inline u32 u2(__half2 v) { return *(u32*)&v; }

// packed-weight FMA: w holds TWO weights (lo,hi); op_sel broadcasts the
// selected half across both lanes of the packed fma. Register-only VALU asm.
__device__ inline void fma_lo(u32& acc, u32 w, u32 x) {
    asm("v_pk_fma_f16 %0, %1, %2, %0 op_sel_hi:[0,1,1]"
        : "+v"(acc) : "v"(w), "v"(x));
}
__device__ inline void fma_hi(u32& acc, u32 w, u32 x) {
    asm("v_pk_fma_f16 %0, %1, %2, %0 op_sel:[1,0,0] op_sel_hi:[1,1,1]"
        : "+v"(acc) : "v"(w), "v"(x));
}

// address-space typedefs for global_load_lds (async global->LDS DMA)
typedef __attribute__((address_space(3))) u32 lds_u32_t;
typedef __attribute__((address_space(1))) const u32 glb_u32_t;

// ---------------------------------------------------------------------------
// prep: Ypad (luma), x state as DEINTERLEAVED half2 planes (even cols -> E,
// odd cols -> O; plane idx = padded_col>>1). buf0 = b (IQ if colored else 0,
// zero halo), buf1 = 0. mask = isColored.
// ---------------------------------------------------------------------------
__global__ __launch_bounds__(256)
void prep_kernel(const float* __restrict__ gray, const float* __restrict__ app,
                 float* __restrict__ Ypad,
                 u32* __restrict__ xE0, u32* __restrict__ xO0,
                 u32* __restrict__ xE1, u32* __restrict__ xO1,
                 unsigned char* __restrict__ mask) {
    int px = blockIdx.x * 64 + threadIdx.x;
    int py = blockIdx.y * 4 + threadIdx.y;
    if (px >= PS || py >= PS) return;
    int i = py - PO, j = px - PO;
    float yv = 0.f;
    float2 bv = make_float2(0.f, 0.f);
    if (i >= 0 && i < Hh && j >= 0 && j < Ww) {
        int idx = i * Ww + j;
        const float s = 1.f / 255.f;
        float gr = gray[idx * 3 + 0] * s;
        float gg = gray[idx * 3 + 1] * s;
        float gb = gray[idx * 3 + 2] * s;
        float ar = app[idx * 3 + 0] * s;
        float ag = app[idx * 3 + 1] * s;
        float ab = app[idx * 3 + 2] * s;
        float diff = fabsf(gr - ar) + fabsf(gg - ag) + fabsf(gb - ab);
        bool colored = diff > 0.01f;
        yv = 0.3f * gr + 0.59f * gg + 0.11f * gb;
        float ay = 0.3f * ar + 0.59f * ag + 0.11f * ab;
        float ai = 0.74f * (ar - ay) - 0.27f * (ab - ay);
        float aq = 0.48f * (ar - ay) + 0.41f * (ab - ay);
        if (colored) bv = make_float2(ai, aq);
        mask[idx] = colored ? 1 : 0;
    }
    Ypad[py * PS + px] = yv;
    u32 hval = u2(__floats2half2_rn(bv.x, bv.y));
    int p = py * PH + (px >> 1);
    if (px & 1) { xO0[p] = hval; xO1[p] = 0u; }
    else        { xE0[p] = hval; xE1[p] = 0u; }
}

// ---------------------------------------------------------------------------
// weights: per padded pixel, 8 normalized neighbor weights packed fp16 (16B).
// ---------------------------------------------------------------------------
__global__ __launch_bounds__(256)
void weights_kernel(const float* __restrict__ Ypad,
                    const unsigned char* __restrict__ mask,
                    W8* __restrict__ w) {
    int px = blockIdx.x * 64 + threadIdx.x;
    int py = blockIdx.y * 4 + threadIdx.y;
    if (px >= PS || py >= PS) return;
    int p = py * PS + px;
    int i = py - PO, j = px - PO;
    W8 out;
    out.a = __floats2half2_rn(0.f, 0.f);
    out.b = out.a; out.c = out.a; out.d = out.a;
    if (i >= 0 && i < Hh && j >= 0 && j < Ww) {
        float yc = Ypad[p];
        float yn[8];
        yn[0] = Ypad[p - PS - 1]; yn[1] = Ypad[p - PS]; yn[2] = Ypad[p - PS + 1];
        yn[3] = Ypad[p - 1];                            yn[4] = Ypad[p + 1];
        yn[5] = Ypad[p + PS - 1]; yn[6] = Ypad[p + PS]; yn[7] = Ypad[p + PS + 1];
        float vt = (i > 0) ? 1.f : 0.f;
        float vb = (i < Hh - 1) ? 1.f : 0.f;
        float vl = (j > 0) ? 1.f : 0.f;
        float vr = (j < Ww - 1) ? 1.f : 0.f;
        float v[8] = { vt * vl, vt, vt * vr, vl, vr, vb * vl, vb, vb * vr };

        float count = 1.f, s1 = yc;
#pragma unroll
        for (int k = 0; k < 8; ++k) { count += v[k]; s1 += v[k] * yn[k]; }
        float mean = s1 / count;
        float var = (yc - mean) * (yc - mean);
#pragma unroll
        for (int k = 0; k < 8; ++k) { float d = yn[k] - mean; var += v[k] * d * d; }
        var /= count;
        float vs = fmaxf(0.6f * var, 2e-6f);
        float inv_vs = 1.f / vs;

        float wk[8], ws = 0.f;
#pragma unroll
        for (int k = 0; k < 8; ++k) {
            float d = yn[k] - yc;
            wk[k] = v[k] * expf(-d * d * inv_vs);
            ws += wk[k];
        }
        if (mask[i * Ww + j]) {
            out.a = __floats2half2_rn(-0.0f, 0.f);  // sign bit => keep center
        } else {
            float scale = 1.f / ws;
            out.a = __floats2half2_rn(wk[0] * scale, wk[1] * scale);
            out.b = __floats2half2_rn(wk[2] * scale, wk[3] * scale);
            out.c = __floats2half2_rn(wk[4] * scale, wk[5] * scale);
            out.d = __floats2half2_rn(wk[6] * scale, wk[7] * scale);
        }
    }
    w[p] = out;
}

// ---------------------------------------------------------------------------
// iter10p R21 == R19 (best measured: 220.9 us). R20's trapezoid shrink
// REVERTED: the t-loop is issue-bound, and the border guards (winit, range
// tests, col mask) cost more issue slots than the skipped border work freed.
// Structure: TILE=64 (1.64x redundancy), deinterleaved E/O planes with odd
// LDS stride 43, packed-weight v_pk_fma op_sel, XCD swizzle, async DMA
// staging. 256 blocks x 1024 threads = 1 block/CU, 16 waves/CU.
// ---------------------------------------------------------------------------
__global__ __launch_bounds__(1024, 4)
void iter10p_kernel(const u32* __restrict__ xE_in, const u32* __restrict__ xO_in,
                    u32* __restrict__ xE_out, u32* __restrict__ xO_out,
                    const W8* __restrict__ w, const float* __restrict__ Ypad,
                    float* __restrict__ out, int writeRGB) {
    __shared__ __align__(16) u32 xs[2][2][PL];   // [buf][plane][row*HS+col/2]
    int tid = threadIdx.x;

    // XCD swizzle (256 % 8 == 0 -> bijective); 16x16 tile grid
    int bid  = (int)blockIdx.y * 16 + (int)blockIdx.x;
    int nbid = (bid & 7) * 32 + (bid >> 3);
    int gi0 = (nbid >> 4) * TILE - T;
    int gj0 = (nbid & 15) * TILE - T;

    // async stage: waves 0..13 stage 6 region rows each (rows 6w..6w+5), both
    // planes; lanes 0..41 carry one u32 per plane-row (42 u32/plane-row).
    {
        int wv = tid >> 6;
        int ln = tid & 63;
        if (wv < 14 && ln < 42) {
            int ch = (gj0 + PO) >> 1;
            const u32* gE = xE_in + (size_t)(gi0 + wv * 6 + PO) * PH + ch + ln;
            const u32* gO = xO_in + (size_t)(gi0 + wv * 6 + PO) * PH + ch + ln;
#pragma unroll 1
            for (int k = 0; k < 6; ++k) {
                __builtin_amdgcn_global_load_lds((glb_u32_t*)(gE + (size_t)k * PH),
                                                 (lds_u32_t*)&xs[0][0][(wv * 6 + k) * HS],
                                                 4, 0, 0);
                __builtin_amdgcn_global_load_lds((glb_u32_t*)(gO + (size_t)k * PH),
                                                 (lds_u32_t*)&xs[0][1][(wv * 6 + k) * HS],
                                                 4, 0, 0);
            }
        }
    }

    // 861 active threads: strip = tid/41 (21 strips of 4 rows), cp = tid%41.
    // rows r0=1+4*strip .. r0+3 (guard r<=82); cols c0=1+2cp (odd), c0+1.
    bool active = tid < 861;
    int strip = tid / 41;
    int cp = tid - strip * 41;
    int r0 = 1 + 4 * strip;
    int c0 = 1 + 2 * cp;

    // weights: up to 4 px-pairs/thread, PACKED (4 u32 per px) + keep-masks.
    // These VMEM loads overlap the staging DMA above.
    u32 wq[4][8];
    u32 kL[4], kR[4];
    if (active) {
#pragma unroll
        for (int i = 0; i < 4; ++i) {
            kL[i] = 0u; kR[i] = 0u;
            if (r0 + i <= 82) {
                int gp = (gi0 + r0 + i + PO) * PS + (gj0 + c0 + PO);
                const uint4* wp = (const uint4*)(w + gp);
                uint4 wa = wp[0];
                uint4 wb = wp[1];
                wq[i][0] = wa.x; wq[i][1] = wa.y; wq[i][2] = wa.z; wq[i][3] = wa.w;
                wq[i][4] = wb.x; wq[i][5] = wb.y; wq[i][6] = wb.z; wq[i][7] = wb.w;
                kL[i] = (wa.x & 0x8000u) ? 0xFFFFFFFFu : 0u;
                kR[i] = (wb.x & 0x8000u) ? 0xFFFFFFFFu : 0u;
            }
        }
    }
    __syncthreads();   // drains the DMA + makes staged region visible

    int cur = 0;
#pragma unroll 1
    for (int t = 0; t < T; ++t) {        // rolled: no t-dependence inside
        int nxt = cur ^ 1;
        if (active) {
            const u32* xe = xs[cur][0];
            const u32* xo = xs[cur][1];
            u32* xen = xs[nxt][0];
            u32* xon = xs[nxt][1];
            int rb = (r0 - 1) * HS + cp;
            // region cols: u0x=2cp, u0y=2cp+1, u1x=2cp+2, u1y=2cp+3
            u32 u0x = xe[rb], u0y = xo[rb], u1x = xe[rb + 1], u1y = xo[rb + 1];
            rb += HS;
            u32 m0x = xe[rb], m0y = xo[rb], m1x = xe[rb + 1], m1y = xo[rb + 1];
#pragma unroll
            for (int i = 0; i < 4; ++i) {
                int r = r0 + i;
                if (r > 82) break;               // last strip: rows 81..82 only
                int rd = (r + 1) * HS + cp;
                u32 d0x = xe[rd], d0y = xo[rd], d1x = xe[rd + 1], d1y = xo[rd + 1];

                u32 accL = kL[i] & m0y;            // center = col c0 (odd)
                fma_lo(accL, wq[i][0], u0x);
                fma_hi(accL, wq[i][0], u0y);
                fma_lo(accL, wq[i][1], u1x);
                fma_hi(accL, wq[i][1], m0x);
                fma_lo(accL, wq[i][2], m1x);
                fma_hi(accL, wq[i][2], d0x);
                fma_lo(accL, wq[i][3], d0y);
                fma_hi(accL, wq[i][3], d1x);

                u32 accR = kR[i] & m1x;            // center = col c0+1 (even)
                fma_lo(accR, wq[i][4], u0y);
                fma_hi(accR, wq[i][4], u1x);
                fma_lo(accR, wq[i][5], u1y);
                fma_hi(accR, wq[i][5], m0y);
                fma_lo(accR, wq[i][6], m1y);
                fma_hi(accR, wq[i][6], d0y);
                fma_lo(accR, wq[i][7], d1x);
                fma_hi(accR, wq[i][7], d1y);

                int wb = r * HS + cp;
                xon[wb]     = accL;                // col c0   (odd plane)
                xen[wb + 1] = accR;                // col c0+1 (even plane)

                u0x = m0x; u0y = m0y; u1x = m1x; u1y = m1y;
                m0x = d0x; m0y = d0y; m1x = d1x; m1y = d1y;
            }
        }
        __syncthreads();
        cur = nxt;
    }

    if (!writeRGB) {
        // write central 64x64 tile (region rows/cols 10..73) to planes
#pragma unroll
        for (int k = 0; k < 4; ++k) {
            int pidx = tid + k * 1024;
            int r = T + (pidx >> 6), c = T + (pidx & 63);
            u32 val = xs[cur][c & 1][r * HS + (c >> 1)];
            u32* pl = (c & 1) ? xO_out : xE_out;
            pl[(size_t)(gi0 + r + PO) * PH + ((gj0 + PO + c) >> 1)] = val;
        }
    } else {
        // fused final: yiq -> rgb, clip, *255 straight from LDS
#pragma unroll
        for (int k = 0; k < 4; ++k) {
            int pidx = tid + k * 1024;
            int r = T + (pidx >> 6), c = T + (pidx & 63);
            int gi = gi0 + r, gj = gj0 + c;
            float y = Ypad[(gi + PO) * PS + (gj + PO)];
            u32 pxv = xs[cur][c & 1][r * HS + (c >> 1)];
            float2 iq = __half22float2(h2(pxv));
            float R_ = y + 0.9468822170900693f * iq.x + 0.6235565819861433f * iq.y;
            float G_ = y - 0.27478764629897834f * iq.x - 0.6356910791873801f * iq.y;
            float B_ = y - 1.1085450346420322f * iq.x + 1.7090069284064666f * iq.y;
            int idx = gi * Ww + gj;
            out[idx * 3 + 0] = fminf(fmaxf(R_, 0.f), 1.f) * 255.f;
            out[idx * 3 + 1] = fminf(fmaxf(G_, 0.f), 1.f) * 255.f;
            out[idx * 3 + 2] = fminf(fmaxf(B_, 0.f), 1.f) * 255.f;
        }
    }
}

extern "C" void kernel_launch(void* const* d_in, const int* in_sizes, int n_in,
                              void* d_out, int out_size, void* d_ws, size_t ws_size,
                              hipStream_t stream) {
    const float* gray = (const float*)d_in[0];
    const float* app  = (const float*)d_in[1];
    float* out = (float*)d_out;

    char* ws = (char*)d_ws;
    size_t off = 0;
    auto alloc = [&](size_t bytes) -> void* {
        void* r = ws + off;
        off = (off + bytes + 255) & ~(size_t)255;
        return r;
    };
    float* Ypad = (float*)alloc((size_t)PS * PS * sizeof(float));
    W8*    w    = (W8*)   alloc((size_t)PS * PS * sizeof(W8));
    unsigned char* mask = (unsigned char*)alloc((size_t)Hh * Ww);
    u32*   xE0  = (u32*)  alloc((size_t)PS * PH * sizeof(u32));
    u32*   xO0  = (u32*)  alloc((size_t)PS * PH * sizeof(u32));
    u32*   xE1  = (u32*)  alloc((size_t)PS * PH * sizeof(u32));
    u32*   xO1  = (u32*)  alloc((size_t)PS * PH * sizeof(u32));

    dim3 blk(64, 4);
    dim3 gridPad((PS + 63) / 64, (PS + 3) / 4);
    prep_kernel<<<gridPad, blk, 0, stream>>>(gray, app, Ypad, xE0, xO0, xE1, xO1, mask);
    weights_kernel<<<gridPad, blk, 0, stream>>>(Ypad, mask, w);

    dim3 gridIter(Ww / TILE, Hh / TILE);  // 16 x 16 = 256 blocks (1 per CU)
    u32 *iE = xE0, *iO = xO0, *oE = xE1, *oO = xO1;
    for (int l = 0; l < 10; ++l) {        // 10 x 10 = 100 iterations
        int last = (l == 9) ? 1 : 0;
        iter10p_kernel<<<gridIter, 1024, 0, stream>>>(iE, iO, oE, oO, w, Ypad, out, last);
        u32* t0 = iE; iE = oE; oE = t0;
        u32* t1 = iO; iO = oO; oO = t1;
    }
}